// Round 5
// baseline (121.886 us; speedup 1.0000x reference)
//
#include <hip/hip_runtime.h>

// GaussianVectorQuantizer on MI355X: N=32768 rows, D=64, K=512, T=0.5
// out[0..2097151] = z_to_decoder [32][64][32][32], out[2097152]=loss, out[2097153]=perplexity
//
// Round 5: pin waves/EU to (2,2) so the allocator gets the full 256-VGPR budget.
//          Round 4 evidence: VGPR_Count stuck at 128 (clang occupancy heuristic,
//          blind to 150KB dynamic LDS) -> acc[32] spills ~76MB/launch to scratch.
//
// ws layout (floats):
//   [0..511]         hp*||c_k||^2 (k_pre)
//   [512]            loss accumulator            (atomic fallback mode)
//   [516..1027]      avg-prob accumulator        (atomic fallback mode)
//   [2048..133119]   per-WG avg-prob partials    (slot mode: wg*512 + tid)
//   [133120..135167] per-wave loss partials      (slot mode)

typedef _Float16 half8 __attribute__((ext_vector_type(8)));
typedef float f32x4 __attribute__((ext_vector_type(4)));

#define SMEM_BYTES 153600
#define WS_FLOATS_NEEDED 135168

__device__ __forceinline__ float half_prec(const float* var_q) {
  float vq = var_q[0];
  float pq = fminf(1.0f / fmaxf(vq, 1e-5f), 1e5f);
  return 0.5f * pq;
}

__global__ void k_pre(const float* __restrict__ var_q,
                      const float* __restrict__ cb,
                      float* __restrict__ ws) {
  int t = threadIdx.x;            // 512 threads
  float hp = half_prec(var_q);
  if (t == 0) ws[512] = 0.0f;     // atomic-mode loss acc
  ws[516 + t] = 0.0f;             // atomic-mode prob acc
  const float4* row = (const float4*)(cb + t * 64);
  float s = 0.0f;
  #pragma unroll
  for (int i = 0; i < 16; ++i) {
    float4 v = row[i];
    s += v.x*v.x + v.y*v.y + v.z*v.z + v.w*v.w;
  }
  ws[t] = hp * s;
}

__global__ void __attribute__((amdgpu_flat_work_group_size(512, 512), amdgpu_waves_per_eu(2, 2)))
k_main(
    const float* __restrict__ z, const float* __restrict__ vq,
    const float* __restrict__ cb, const float* __restrict__ gu,
    float* __restrict__ out, float* __restrict__ ws, int slot)
{
  extern __shared__ char smem[];
  _Float16* lB1 = (_Float16*)smem;               // 65536 B: pass1 B fragments
  _Float16* lB2 = (_Float16*)(smem + 65536);     // 65536 B: pass2 B fragments
  char*  chunkAll = smem + 131072;               // 8 waves x 2560 B
  float* pr = (float*)(smem + 151552);           // 512 f32 prob accumulator

  const int tid  = threadIdx.x;
  const int lane = tid & 63;
  const int wv   = tid >> 6;
  const int c    = lane & 15;     // within-tile col / z-row slot
  const int g    = lane >> 4;     // k-group

  pr[tid] = 0.0f;

  // ---- stage codebook into MFMA-fragment order ----
  // cbB1[t*2+kk][l][j] = f16 cb[code=(l&15)*32+t][dim=32*kk+8*(l>>4)+j]
  #pragma unroll
  for (int i = 0; i < 8; ++i) {
    int F = tid + 512*i;
    int l = F & 63, grp = F >> 6;
    int t = grp >> 1, kk = grp & 1;
    int cc = l & 15, gg = l >> 4;
    const float* src = cb + (cc*32 + t)*64 + kk*32 + gg*8;
    float4 v0 = *(const float4*)src;
    float4 v1 = *(const float4*)(src + 4);
    half8 h = { (_Float16)v0.x, (_Float16)v0.y, (_Float16)v0.z, (_Float16)v0.w,
                (_Float16)v1.x, (_Float16)v1.y, (_Float16)v1.z, (_Float16)v1.w };
    ((half8*)lB1)[F] = h;
  }
  // cbB2[kt*4+nt][l][j] = f16 cb[code=((kap&15)<<5)+2*kt+(kap>>4)][dim=nt*16+(l&15)], kap=8*(l>>4)+j
  #pragma unroll
  for (int i = 0; i < 8; ++i) {
    int F = tid + 512*i;
    int l = F & 63, grp = F >> 6;
    int kt = grp >> 2, nt = grp & 3;
    int cc = l & 15, gg = l >> 4;
    int dim = nt*16 + cc;
    half8 h;
    #pragma unroll
    for (int j = 0; j < 8; ++j) {
      int kap = gg*8 + j;
      int code = ((kap & 15) << 5) + 2*kt + (kap >> 4);
      h[j] = (_Float16)cb[code*64 + dim];
    }
    ((half8*)lB2)[F] = h;
  }
  __syncthreads();

  const float hp   = half_prec(vq);
  const float s2hp = 2.0f * hp;

  const int row0 = (blockIdx.x * 8 + wv) * 16;   // 16 rows per wave
  const int b    = row0 >> 10;
  const int wh0  = row0 & 1023;

  _Float16* myChunk = (_Float16*)(chunkAll + wv * 2560);

  // ---- z loaded ONCE, coalesced (lane = dim, 16 wh values) ----
  float zr[16];
  {
    const float* zp = z + ((size_t)(b*64 + lane) << 10) + wh0;
    #pragma unroll
    for (int s4 = 0; s4 < 4; ++s4) {
      float4 v = *(const float4*)(zp + 4*s4);
      zr[4*s4+0]=v.x; zr[4*s4+1]=v.y; zr[4*s4+2]=v.z; zr[4*s4+3]=v.w;
    }
  }
  // stage scaled f16 copy: zc[wh s][dim], row stride 72 halfs
  _Float16* zc = myChunk;
  #pragma unroll
  for (int s = 0; s < 16; ++s) zc[s*72 + lane] = (_Float16)(zr[s] * s2hp);

  // ---- acc init: -hp*||c_k||^2, code = c*32+t ----
  f32x4 acc[32];
  {
    const float4* hn = (const float4*)(ws + c*32);
    #pragma unroll
    for (int u = 0; u < 8; ++u) {
      float4 h4 = hn[u];
      acc[4*u+0] = (f32x4){-h4.x, -h4.x, -h4.x, -h4.x};
      acc[4*u+1] = (f32x4){-h4.y, -h4.y, -h4.y, -h4.y};
      acc[4*u+2] = (f32x4){-h4.z, -h4.z, -h4.z, -h4.z};
      acc[4*u+3] = (f32x4){-h4.w, -h4.w, -h4.w, -h4.w};
    }
  }

  // A-frags from LDS (row = c, k = g*8+j / 32+g*8+j)
  half8 zA0 = *(const half8*)(zc + c*72 + g*8);
  half8 zA1 = *(const half8*)(zc + c*72 + 32 + g*8);

  // ---- pass 1: 64 MFMA -> acc[t][q] = logit[row 4g+q][code c*32+t] ----
  const half8* B1 = (const half8*)lB1;
  #pragma unroll
  for (int t = 0; t < 32; ++t) {
    acc[t] = __builtin_amdgcn_mfma_f32_16x16x32_f16(zA0, B1[(t*2+0)*64 + lane], acc[t], 0, 0, 0);
    acc[t] = __builtin_amdgcn_mfma_f32_16x16x32_f16(zA1, B1[(t*2+1)*64 + lane], acc[t], 0, 0, 0);
  }

  // ---- softmax stats (rows 4g+q; reduce across the 16 lanes of group g) ----
  float mq[4];
  #pragma unroll
  for (int q = 0; q < 4; ++q) {
    float m = acc[0][q];
    #pragma unroll
    for (int t = 1; t < 32; ++t) m = fmaxf(m, acc[t][q]);
    #pragma unroll
    for (int o = 8; o > 0; o >>= 1) m = fmaxf(m, __shfl_xor(m, o));
    mq[q] = m;
  }
  #pragma unroll
  for (int t = 0; t < 32; ++t)
    #pragma unroll
    for (int q = 0; q < 4; ++q) acc[t][q] -= mq[q];

  float s1[4] = {0,0,0,0}, pl[4] = {0,0,0,0};
  #pragma unroll
  for (int t = 0; t < 32; ++t)
    #pragma unroll
    for (int q = 0; q < 4; ++q) {
      float p = __expf(acc[t][q]);
      s1[q] += p;
      pl[q] = fmaf(p, acc[t][q], pl[q]);
    }
  float kd = 0.0f, inv1[4];
  #pragma unroll
  for (int q = 0; q < 4; ++q) {
    #pragma unroll
    for (int o = 8; o > 0; o >>= 1) { s1[q] += __shfl_xor(s1[q], o); pl[q] += __shfl_xor(pl[q], o); }
    inv1[q] = 1.0f / s1[q];
    kd += pl[q] * inv1[q] - __logf(s1[q]);
  }

  // ---- avg-prob accumulation (codes c*32+t), pr layout [t][c] ----
  #pragma unroll
  for (int t = 0; t < 32; ++t) {
    float v = 0.0f;
    #pragma unroll
    for (int q = 0; q < 4; ++q) v = fmaf(__expf(acc[t][q]), inv1[q], v);
    v += __shfl_xor(v, 16);
    v += __shfl_xor(v, 32);
    if (g == 0) atomicAdd(&pr[t*16 + c], v);
  }

  // ---- gumbel-softmax logits: acc <- 2*(l + gv); one q at a time (reg pressure) ----
  #pragma unroll
  for (int q = 0; q < 4; ++q) {
    const float4* ub = (const float4*)(gu + ((size_t)(row0 + 4*g + q)) * 512 + c*32);
    #pragma unroll
    for (int tt = 0; tt < 8; ++tt) {
      float4 u4 = ub[tt];
      float y0 = 1e-10f - __logf(u4.x + 1e-10f);
      float y1 = 1e-10f - __logf(u4.y + 1e-10f);
      float y2 = 1e-10f - __logf(u4.z + 1e-10f);
      float y3 = 1e-10f - __logf(u4.w + 1e-10f);
      acc[4*tt+0][q] = 2.0f * (acc[4*tt+0][q] - __logf(y0));
      acc[4*tt+1][q] = 2.0f * (acc[4*tt+1][q] - __logf(y1));
      acc[4*tt+2][q] = 2.0f * (acc[4*tt+2][q] - __logf(y2));
      acc[4*tt+3][q] = 2.0f * (acc[4*tt+3][q] - __logf(y3));
    }
  }

  // ---- encoding softmax (in-place) ----
  #pragma unroll
  for (int q = 0; q < 4; ++q) {
    float m = acc[0][q];
    #pragma unroll
    for (int t = 1; t < 32; ++t) m = fmaxf(m, acc[t][q]);
    #pragma unroll
    for (int o = 8; o > 0; o >>= 1) m = fmaxf(m, __shfl_xor(m, o));
    float s = 0.0f;
    #pragma unroll
    for (int t = 0; t < 32; ++t) { float e = __expf(acc[t][q] - m); acc[t][q] = e; s += e; }
    #pragma unroll
    for (int o = 8; o > 0; o >>= 1) s += __shfl_xor(s, o);
    float inv = 1.0f / s;
    #pragma unroll
    for (int t = 0; t < 32; ++t) acc[t][q] *= inv;
  }

  // ---- pass 2: zq[16x64] = enc @ cb, chunked through per-wave LDS ----
  f32x4 zacc[4];
  #pragma unroll
  for (int nt = 0; nt < 4; ++nt) zacc[nt] = (f32x4){0.f, 0.f, 0.f, 0.f};

  const half8* B2 = (const half8*)lB2;
  #pragma unroll
  for (int kt = 0; kt < 16; ++kt) {
    _Float16* eS = myChunk + (kt & 1) * 640;     // [16 rows][40 halfs]
    #pragma unroll
    for (int tb = 0; tb < 2; ++tb)
      #pragma unroll
      for (int q = 0; q < 4; ++q)
        eS[(4*g + q)*40 + 16*tb + c] = (_Float16)acc[2*kt + tb][q];
    half8 ea = *(const half8*)(eS + c*40 + g*8); // A-frag: row=c, k=8g+j
    #pragma unroll
    for (int nt = 0; nt < 4; ++nt)
      zacc[nt] = __builtin_amdgcn_mfma_f32_16x16x32_f16(ea, B2[(kt*4 + nt)*64 + lane], zacc[nt], 0, 0, 0);
  }

  // ---- stage zq (f16), transpose to lane=dim, store + continuous KLD ----
  _Float16* zS = myChunk;                        // [16 rows][72 halfs]
  #pragma unroll
  for (int nt = 0; nt < 4; ++nt)
    #pragma unroll
    for (int q = 0; q < 4; ++q)
      zS[(4*g + q)*72 + nt*16 + c] = (_Float16)zacc[nt][q];

  float kc = 0.0f;
  {
    float* orow = out + ((size_t)(b*64 + lane) << 10) + wh0;
    #pragma unroll
    for (int s4 = 0; s4 < 4; ++s4) {
      float4 ov;
      ov.x = (float)zS[(4*s4 + 0)*72 + lane];
      ov.y = (float)zS[(4*s4 + 1)*72 + lane];
      ov.z = (float)zS[(4*s4 + 2)*72 + lane];
      ov.w = (float)zS[(4*s4 + 3)*72 + lane];
      float d0 = zr[4*s4+0] - ov.x, d1 = zr[4*s4+1] - ov.y;
      float d2 = zr[4*s4+2] - ov.z, d3 = zr[4*s4+3] - ov.w;
      kc = fmaf(d0, d0, kc); kc = fmaf(d1, d1, kc);
      kc = fmaf(d2, d2, kc); kc = fmaf(d3, d3, kc);
      *(float4*)(orow + 4*s4) = ov;
    }
  }
  kc *= hp;

  // ---- loss partial: kd duplicated over 16 c-lanes (/16), kc unique per lane ----
  float lv = kd * 0.0625f + kc;
  #pragma unroll
  for (int o = 32; o > 0; o >>= 1) lv += __shfl_xor(lv, o);
  if (lane == 0) {
    if (slot) ws[133120 + blockIdx.x*8 + wv] = lv;
    else      atomicAdd(&ws[512], lv);
  }

  __syncthreads();
  if (slot) {
    ws[2048 + blockIdx.x*512 + tid] = pr[tid];   // raw pr layout (permutation not needed)
  } else {
    atomicAdd(ws + 516 + tid, pr[tid]);
  }
}

__global__ void k_fin(const float* __restrict__ ws, float* __restrict__ out, int slot) {
  __shared__ float redH[16], redL[16];
  int t = threadIdx.x;  // 1024
  float h = 0.0f, l = 0.0f;
  if (slot) {
    if (t < 512) {
      float s = 0.0f;
      #pragma unroll 8
      for (int wg = 0; wg < 256; ++wg) s += ws[2048 + wg*512 + t];   // coalesced
      float a = fmaxf(s * (1.0f/32768.0f), 1e-10f);
      h = -a * __logf(a + 1e-10f);
    } else {
      int x = t - 512;
      #pragma unroll
      for (int i = 0; i < 4; ++i) l += ws[133120 + x + 512*i];
    }
  } else {
    if (t < 512) {
      float a = fmaxf(ws[516 + t] * (1.0f/32768.0f), 1e-10f);
      h = -a * __logf(a + 1e-10f);
    } else if (t == 512) {
      l = ws[512];
    }
  }
  #pragma unroll
  for (int o = 32; o > 0; o >>= 1) { h += __shfl_xor(h, o); l += __shfl_xor(l, o); }
  if ((t & 63) == 0) { redH[t >> 6] = h; redL[t >> 6] = l; }
  __syncthreads();
  if (t == 0) {
    float H = 0.0f, L = 0.0f;
    #pragma unroll
    for (int i = 0; i < 16; ++i) { H += redH[i]; L += redL[i]; }
    out[2097152] = L * (1.0f/32.0f);
    out[2097153] = __expf(H);
  }
}

extern "C" void kernel_launch(void* const* d_in, const int* in_sizes, int n_in,
                              void* d_out, int out_size, void* d_ws, size_t ws_size,
                              hipStream_t stream) {
  const float* z  = (const float*)d_in[0];
  const float* vq = (const float*)d_in[1];
  const float* cb = (const float*)d_in[2];
  const float* gu = (const float*)d_in[3];
  float* out = (float*)d_out;
  float* ws  = (float*)d_ws;
  int slot = (ws_size >= (size_t)WS_FLOATS_NEEDED * 4) ? 1 : 0;

  hipFuncSetAttribute((const void*)k_main, hipFuncAttributeMaxDynamicSharedMemorySize, SMEM_BYTES);

  hipLaunchKernelGGL(k_pre,  dim3(1),   dim3(512),  0,          stream, vq, cb, ws);
  hipLaunchKernelGGL(k_main, dim3(256), dim3(512),  SMEM_BYTES, stream, z, vq, cb, gu, out, ws, slot);
  hipLaunchKernelGGL(k_fin,  dim3(1),   dim3(1024), 0,          stream, ws, out, slot);
}

// Round 6
// 74.844 us; speedup vs baseline: 1.6285x; 1.6285x over previous
//
#include <hip/hip_runtime.h>

// GaussianVectorQuantizer on MI355X: N=32768 rows, D=64, K=512, T=0.5
// out[0..2097151] = z_to_decoder [32][64][32][32], out[2097152]=loss, out[2097153]=perplexity
//
// Round 6: wave-pair code-split. Rounds 3-5 proved acc[32] (128 f32/lane) spills
//          ~83 MB/launch to scratch at the allocator's hard 128-VGPR choice.
//          Now each 16-row tile is shared by TWO waves, each owning 256 codes:
//          acc[16] = 64 regs/lane -> no spill possible. Softmax reductions and
//          the pass-2 zq partial sum go through small LDS buffers.
//
// ws layout (floats):
//   [0..511]          hp*||c_k||^2 (k_pre)
//   [512]             loss accumulator          (atomic fallback)
//   [516..1027]       avg-prob accumulator      (atomic fallback)
//   [2048..264191]    per-WG avg-prob partials  (slot: wg*512 + tid, 512 WGs)
//   [264192..268287]  per-wave loss partials    (slot: wg*8 + wave, 4096)
//   [268288..284671]  k_red partials            (32 x 512)

typedef _Float16 half8 __attribute__((ext_vector_type(8)));
typedef float f32x4 __attribute__((ext_vector_type(4)));

#define SMEM_BYTES 155136
#define WS_FLOATS_NEEDED 284672

__device__ __forceinline__ float half_prec(const float* var_q) {
  float vq = var_q[0];
  float pq = fminf(1.0f / fmaxf(vq, 1e-5f), 1e5f);
  return 0.5f * pq;
}

__global__ void k_pre(const float* __restrict__ var_q,
                      const float* __restrict__ cb,
                      float* __restrict__ ws) {
  int t = threadIdx.x;            // 512 threads
  float hp = half_prec(var_q);
  if (t == 0) ws[512] = 0.0f;     // atomic-mode loss acc
  ws[516 + t] = 0.0f;             // atomic-mode prob acc
  const float4* row = (const float4*)(cb + t * 64);
  float s = 0.0f;
  #pragma unroll
  for (int i = 0; i < 16; ++i) {
    float4 v = row[i];
    s += v.x*v.x + v.y*v.y + v.z*v.z + v.w*v.w;
  }
  ws[t] = hp * s;
}

__global__ void __attribute__((amdgpu_flat_work_group_size(512, 512), amdgpu_waves_per_eu(2, 2)))
k_main(
    const float* __restrict__ z, const float* __restrict__ vq,
    const float* __restrict__ cb, const float* __restrict__ gu,
    float* __restrict__ out, float* __restrict__ ws, int slot)
{
  extern __shared__ char smem[];
  _Float16* lB1 = (_Float16*)smem;               // 65536 B: pass1 B fragments (32 tiles)
  _Float16* lB2 = (_Float16*)(smem + 65536);     // 65536 B: pass2 B fragments (16 tiles)
  char*  chunkAll = smem + 131072;               // 20480 B: zc (pair) / eS (wave) / zqx (pair)
  float* pr   = (float*)(smem + 151552);         // 512 f32 prob accumulator
  float* redM = (float*)(smem + 153600);         // [4 pairs][2 halves][16 rows]
  float* redS = (float*)(smem + 154112);
  float* redP = (float*)(smem + 154624);

  const int tid  = threadIdx.x;
  const int lane = tid & 63;
  const int wv   = tid >> 6;
  const int h    = wv & 1;        // code half: codes with (code&31) in [16h, 16h+16)
  const int p    = wv >> 1;       // row-tile pair index (0..3)
  const int c    = lane & 15;     // tile col / row slot
  const int g    = lane >> 4;     // k-group

  pr[tid] = 0.0f;

  // ---- stage codebook into MFMA-fragment order (same layouts as rounds 2-5) ----
  // cbB1[tt*2+kk][l][j] = f16 cb[code=(l&15)*32+tt][dim=32*kk+8*(l>>4)+j]
  #pragma unroll
  for (int i = 0; i < 8; ++i) {
    int F = tid + 512*i;
    int l = F & 63, grp = F >> 6;
    int t = grp >> 1, kk = grp & 1;
    int cc = l & 15, gg = l >> 4;
    const float* src = cb + (cc*32 + t)*64 + kk*32 + gg*8;
    float4 v0 = *(const float4*)src;
    float4 v1 = *(const float4*)(src + 4);
    half8 hh = { (_Float16)v0.x, (_Float16)v0.y, (_Float16)v0.z, (_Float16)v0.w,
                 (_Float16)v1.x, (_Float16)v1.y, (_Float16)v1.z, (_Float16)v1.w };
    ((half8*)lB1)[F] = hh;
  }
  // cbB2[kt*4+nt][l][j] = f16 cb[code=((kap&15)<<5)+2*kt+(kap>>4)][dim=nt*16+(l&15)], kap=8*(l>>4)+j
  #pragma unroll
  for (int i = 0; i < 8; ++i) {
    int F = tid + 512*i;
    int l = F & 63, grp = F >> 6;
    int kt = grp >> 2, nt = grp & 3;
    int cc = l & 15, gg = l >> 4;
    int dim = nt*16 + cc;
    half8 hh;
    #pragma unroll
    for (int j = 0; j < 8; ++j) {
      int kap = gg*8 + j;
      int code = ((kap & 15) << 5) + 2*kt + (kap >> 4);
      hh[j] = (_Float16)cb[code*64 + dim];
    }
    ((half8*)lB2)[F] = hh;
  }

  const float hp   = half_prec(vq);
  const float s2hp = 2.0f * hp;

  const int row0 = (blockIdx.x * 4 + p) * 16;    // 16 rows per PAIR
  const int b    = row0 >> 10;
  const int wh0  = row0 & 1023;

  _Float16* zc = (_Float16*)(chunkAll + p * 5120);   // [16 rows][72 halfs], pair-shared

  // ---- z: each wave loads & stages ITS 8 rows (lane = dim), coalesced ----
  float zr[8];
  {
    const float* zp = z + ((size_t)(b*64 + lane) << 10) + wh0 + 8*h;
    float4 v0 = *(const float4*)zp;
    float4 v1 = *(const float4*)(zp + 4);
    zr[0]=v0.x; zr[1]=v0.y; zr[2]=v0.z; zr[3]=v0.w;
    zr[4]=v1.x; zr[5]=v1.y; zr[6]=v1.z; zr[7]=v1.w;
  }
  #pragma unroll
  for (int s = 0; s < 8; ++s) zc[(8*h + s)*72 + lane] = (_Float16)(zr[s] * s2hp);

  __syncthreads();   // B1, B2, zc visible

  // ---- acc init: -hp*||c_k||^2 for codes c*32 + h*16 + t ----
  f32x4 acc[16];
  {
    const float4* hn = (const float4*)(ws + c*32 + h*16);
    #pragma unroll
    for (int u = 0; u < 4; ++u) {
      float4 h4 = hn[u];
      acc[4*u+0] = (f32x4){-h4.x, -h4.x, -h4.x, -h4.x};
      acc[4*u+1] = (f32x4){-h4.y, -h4.y, -h4.y, -h4.y};
      acc[4*u+2] = (f32x4){-h4.z, -h4.z, -h4.z, -h4.z};
      acc[4*u+3] = (f32x4){-h4.w, -h4.w, -h4.w, -h4.w};
    }
  }

  // A-frags (identical for both waves of the pair): row=c, k=g*8+j / 32+g*8+j
  half8 zA0 = *(const half8*)(zc + c*72 + g*8);
  half8 zA1 = *(const half8*)(zc + c*72 + 32 + g*8);

  // ---- pass 1: 32 MFMA -> acc[t][q] = logit[row 4g+q][code c*32+h*16+t] ----
  const half8* B1 = (const half8*)lB1;
  #pragma unroll
  for (int t = 0; t < 16; ++t) {
    int tt = h*16 + t;
    acc[t] = __builtin_amdgcn_mfma_f32_16x16x32_f16(zA0, B1[(tt*2+0)*64 + lane], acc[t], 0, 0, 0);
    acc[t] = __builtin_amdgcn_mfma_f32_16x16x32_f16(zA1, B1[(tt*2+1)*64 + lane], acc[t], 0, 0, 0);
  }

  const int rix = p*32 + h*16;     // this wave's red-buffer base

  // ---- softmax max: intra-wave (16 c-lanes) then cross-wave via LDS ----
  #pragma unroll
  for (int q = 0; q < 4; ++q) {
    float m = acc[0][q];
    #pragma unroll
    for (int t = 1; t < 16; ++t) m = fmaxf(m, acc[t][q]);
    #pragma unroll
    for (int o = 8; o > 0; o >>= 1) m = fmaxf(m, __shfl_xor(m, o));
    if (c == 0) redM[rix + 4*g + q] = m;
  }
  __syncthreads();
  float mq[4];
  #pragma unroll
  for (int q = 0; q < 4; ++q)
    mq[q] = fmaxf(redM[p*32 + 4*g + q], redM[p*32 + 16 + 4*g + q]);
  #pragma unroll
  for (int t = 0; t < 16; ++t)
    #pragma unroll
    for (int q = 0; q < 4; ++q) acc[t][q] -= mq[q];

  // ---- exp-sums (s1) and p*logit sums (pl) ----
  {
    float s1[4] = {0,0,0,0}, pl[4] = {0,0,0,0};
    #pragma unroll
    for (int t = 0; t < 16; ++t)
      #pragma unroll
      for (int q = 0; q < 4; ++q) {
        float e = __expf(acc[t][q]);
        s1[q] += e;
        pl[q] = fmaf(e, acc[t][q], pl[q]);
      }
    #pragma unroll
    for (int q = 0; q < 4; ++q) {
      #pragma unroll
      for (int o = 8; o > 0; o >>= 1) { s1[q] += __shfl_xor(s1[q], o); pl[q] += __shfl_xor(pl[q], o); }
      if (c == 0) { redS[rix + 4*g + q] = s1[q]; redP[rix + 4*g + q] = pl[q]; }
    }
  }
  __syncthreads();
  float kd = 0.0f, inv1[4];
  #pragma unroll
  for (int q = 0; q < 4; ++q) {
    float S = redS[p*32 + 4*g + q] + redS[p*32 + 16 + 4*g + q];
    float P = redP[p*32 + 4*g + q] + redP[p*32 + 16 + 4*g + q];
    inv1[q] = 1.0f / S;
    kd += P * inv1[q] - __logf(S);
  }

  // ---- avg-prob accumulation: code c*32+h*16+t -> pr[(h*16+t)*16 + c] ----
  #pragma unroll
  for (int t = 0; t < 16; ++t) {
    float v = 0.0f;
    #pragma unroll
    for (int q = 0; q < 4; ++q) v = fmaf(__expf(acc[t][q]), inv1[q], v);
    v += __shfl_xor(v, 16);
    v += __shfl_xor(v, 32);
    if (g == 0) atomicAdd(&pr[(h*16 + t)*16 + c], v);
  }

  // ---- gumbel: acc <- 2*(l + gv), gv = -log(-log(u+eps)+eps) ----
  #pragma unroll
  for (int q = 0; q < 4; ++q) {
    const float4* ub = (const float4*)(gu + ((size_t)(row0 + 4*g + q))*512 + c*32 + h*16);
    #pragma unroll
    for (int tt = 0; tt < 4; ++tt) {
      float4 u4 = ub[tt];
      float y0 = 1e-10f - __logf(u4.x + 1e-10f);
      float y1 = 1e-10f - __logf(u4.y + 1e-10f);
      float y2 = 1e-10f - __logf(u4.z + 1e-10f);
      float y3 = 1e-10f - __logf(u4.w + 1e-10f);
      acc[4*tt+0][q] = 2.0f * (acc[4*tt+0][q] - __logf(y0));
      acc[4*tt+1][q] = 2.0f * (acc[4*tt+1][q] - __logf(y1));
      acc[4*tt+2][q] = 2.0f * (acc[4*tt+2][q] - __logf(y2));
      acc[4*tt+3][q] = 2.0f * (acc[4*tt+3][q] - __logf(y3));
    }
  }

  // ---- encoding softmax: max then sum, both pair-combined ----
  #pragma unroll
  for (int q = 0; q < 4; ++q) {
    float m = acc[0][q];
    #pragma unroll
    for (int t = 1; t < 16; ++t) m = fmaxf(m, acc[t][q]);
    #pragma unroll
    for (int o = 8; o > 0; o >>= 1) m = fmaxf(m, __shfl_xor(m, o));
    if (c == 0) redM[rix + 4*g + q] = m;
  }
  __syncthreads();
  #pragma unroll
  for (int q = 0; q < 4; ++q) {
    float m2 = fmaxf(redM[p*32 + 4*g + q], redM[p*32 + 16 + 4*g + q]);
    float s = 0.0f;
    #pragma unroll
    for (int t = 0; t < 16; ++t) { float e = __expf(acc[t][q] - m2); acc[t][q] = e; s += e; }
    #pragma unroll
    for (int o = 8; o > 0; o >>= 1) s += __shfl_xor(s, o);
    if (c == 0) redS[rix + 4*g + q] = s;
  }
  __syncthreads();
  #pragma unroll
  for (int q = 0; q < 4; ++q) {
    float inv = 1.0f / (redS[p*32 + 4*g + q] + redS[p*32 + 16 + 4*g + q]);
    #pragma unroll
    for (int t = 0; t < 16; ++t) acc[t][q] *= inv;
  }

  // ---- pass 2: partial zq over this wave's 256 codes (tiles kt = h*8+k) ----
  f32x4 zacc[4];
  #pragma unroll
  for (int nt = 0; nt < 4; ++nt) zacc[nt] = (f32x4){0.f, 0.f, 0.f, 0.f};

  const half8* B2 = (const half8*)lB2;
  _Float16* myES = (_Float16*)(chunkAll + wv * 2560);
  #pragma unroll
  for (int k = 0; k < 8; ++k) {
    _Float16* eS = myES + (k & 1) * 640;     // [16 rows][40 halfs], wave-private
    #pragma unroll
    for (int tb = 0; tb < 2; ++tb)
      #pragma unroll
      for (int q = 0; q < 4; ++q)
        eS[(4*g + q)*40 + 16*tb + c] = (_Float16)acc[2*k + tb][q];
    half8 ea = *(const half8*)(eS + c*40 + g*8); // A-frag: row=c, kap=8g+j
    int kt = h*8 + k;
    #pragma unroll
    for (int nt = 0; nt < 4; ++nt)
      zacc[nt] = __builtin_amdgcn_mfma_f32_16x16x32_f16(ea, B2[(kt*4 + nt)*64 + lane], zacc[nt], 0, 0, 0);
  }

  // ---- pair-sum zq through LDS (f32), then transpose-store + continuous KLD ----
  __syncthreads();                                   // eS regions dead everywhere
  float* zqx = (float*)chunkAll + p * 1056;          // [16 rows][66 f32], pair-shared
  if (h) {
    #pragma unroll
    for (int nt = 0; nt < 4; ++nt)
      #pragma unroll
      for (int q = 0; q < 4; ++q)
        zqx[(4*g + q)*66 + nt*16 + c] = zacc[nt][q];
  }
  __syncthreads();
  if (!h) {
    #pragma unroll
    for (int nt = 0; nt < 4; ++nt)
      #pragma unroll
      for (int q = 0; q < 4; ++q) {
        int ix = (4*g + q)*66 + nt*16 + c;
        zqx[ix] += zacc[nt][q];
      }
  }
  __syncthreads();

  float kc = 0.0f;
  {
    float* orow = out + ((size_t)(b*64 + lane) << 10) + wh0 + 8*h;
    float4 o0, o1;
    o0.x = zqx[(8*h + 0)*66 + lane]; o0.y = zqx[(8*h + 1)*66 + lane];
    o0.z = zqx[(8*h + 2)*66 + lane]; o0.w = zqx[(8*h + 3)*66 + lane];
    o1.x = zqx[(8*h + 4)*66 + lane]; o1.y = zqx[(8*h + 5)*66 + lane];
    o1.z = zqx[(8*h + 6)*66 + lane]; o1.w = zqx[(8*h + 7)*66 + lane];
    float d;
    d = zr[0]-o0.x; kc = fmaf(d,d,kc);  d = zr[1]-o0.y; kc = fmaf(d,d,kc);
    d = zr[2]-o0.z; kc = fmaf(d,d,kc);  d = zr[3]-o0.w; kc = fmaf(d,d,kc);
    d = zr[4]-o1.x; kc = fmaf(d,d,kc);  d = zr[5]-o1.y; kc = fmaf(d,d,kc);
    d = zr[6]-o1.z; kc = fmaf(d,d,kc);  d = zr[7]-o1.w; kc = fmaf(d,d,kc);
    *(float4*)orow       = o0;
    *(float4*)(orow + 4) = o1;
  }
  kc *= hp;

  // ---- loss partial: kd only from h==0 (dup x16 c-lanes), kc from both halves ----
  float lv = (h ? 0.0f : kd * 0.0625f) + kc;
  #pragma unroll
  for (int o = 32; o > 0; o >>= 1) lv += __shfl_xor(lv, o);
  if (lane == 0) {
    if (slot) ws[264192 + blockIdx.x*8 + wv] = lv;
    else      atomicAdd(&ws[512], lv);
  }

  __syncthreads();
  if (slot) {
    ws[2048 + (size_t)blockIdx.x*512 + tid] = pr[tid];
  } else {
    atomicAdd(ws + 516 + tid, pr[tid]);
  }
}

// slot mode: 32 WGs, each folds 16 WG-chunks of avg-prob partials
__global__ void k_red(float* __restrict__ ws) {
  int gix = blockIdx.x, t = threadIdx.x;   // 32 x 512
  float s = 0.0f;
  #pragma unroll 4
  for (int i = 0; i < 16; ++i) s += ws[2048 + (size_t)(gix*16 + i)*512 + t];
  ws[268288 + gix*512 + t] = s;
}

__global__ void k_fin(const float* __restrict__ ws, float* __restrict__ out, int slot) {
  __shared__ float redH[16], redL[16];
  int t = threadIdx.x;  // 1024
  float h = 0.0f, l = 0.0f;
  if (slot) {
    if (t < 512) {
      float s = 0.0f;
      #pragma unroll
      for (int g = 0; g < 32; ++g) s += ws[268288 + g*512 + t];
      float a = fmaxf(s * (1.0f/32768.0f), 1e-10f);
      h = -a * __logf(a + 1e-10f);
    } else {
      int x = t - 512;
      #pragma unroll
      for (int i = 0; i < 8; ++i) l += ws[264192 + x + 512*i];
    }
  } else {
    if (t < 512) {
      float a = fmaxf(ws[516 + t] * (1.0f/32768.0f), 1e-10f);
      h = -a * __logf(a + 1e-10f);
    } else if (t == 512) {
      l = ws[512];
    }
  }
  #pragma unroll
  for (int o = 32; o > 0; o >>= 1) { h += __shfl_xor(h, o); l += __shfl_xor(l, o); }
  if ((t & 63) == 0) { redH[t >> 6] = h; redL[t >> 6] = l; }
  __syncthreads();
  if (t == 0) {
    float H = 0.0f, L = 0.0f;
    #pragma unroll
    for (int i = 0; i < 16; ++i) { H += redH[i]; L += redL[i]; }
    out[2097152] = L * (1.0f/32.0f);
    out[2097153] = __expf(H);
  }
}

extern "C" void kernel_launch(void* const* d_in, const int* in_sizes, int n_in,
                              void* d_out, int out_size, void* d_ws, size_t ws_size,
                              hipStream_t stream) {
  const float* z  = (const float*)d_in[0];
  const float* vq = (const float*)d_in[1];
  const float* cb = (const float*)d_in[2];
  const float* gu = (const float*)d_in[3];
  float* out = (float*)d_out;
  float* ws  = (float*)d_ws;
  int slot = (ws_size >= (size_t)WS_FLOATS_NEEDED * 4) ? 1 : 0;

  hipFuncSetAttribute((const void*)k_main, hipFuncAttributeMaxDynamicSharedMemorySize, SMEM_BYTES);

  hipLaunchKernelGGL(k_pre,  dim3(1),   dim3(512),  0,          stream, vq, cb, ws);
  hipLaunchKernelGGL(k_main, dim3(512), dim3(512),  SMEM_BYTES, stream, z, vq, cb, gu, out, ws, slot);
  if (slot) hipLaunchKernelGGL(k_red, dim3(32), dim3(512), 0, stream, ws);
  hipLaunchKernelGGL(k_fin,  dim3(1),   dim3(1024), 0,          stream, ws, out, slot);
}

// Round 7
// 68.564 us; speedup vs baseline: 1.7777x; 1.0916x over previous
//
#include <hip/hip_runtime.h>

// GaussianVectorQuantizer on MI355X: N=32768 rows, D=64, K=512, T=0.5
// out[0..2097151] = z_to_decoder [32][64][32][32], out[2097152]=loss, out[2097153]=perplexity
//
// Round 7: occupancy. Round 6 fixed spills (WRITE 92.7->9.2 MB) but ran at 8 waves/CU
//          (150 KB LDS + waves_per_eu(2,2) pin). Now codebook MFMA fragments are
//          pre-formatted ONCE in k_pre into ws; k_main reads them global->VGPR
//          (coalesced dwordx4, L2-resident). LDS: 151.5 KB -> 23.5 KB => 2 WGs/CU.
//
// ws layout (floats):
//   [0..511]          hp*||c_k||^2
//   [512]             loss accumulator          (atomic fallback)
//   [516..1027]       avg-prob accumulator      (atomic fallback)
//   [4096..20479]     B1 fragments (64 KB)      (pre mode)
//   [20480..36863]    B2 fragments (64 KB)      (pre mode)
//   [36864..299007]   per-WG avg-prob partials  (pre: wg*512 + tid, 512 WGs)
//   [299008..303103]  per-wave loss partials    (pre: wg*8 + wave)
//   [303104..319487]  k_red partials            (32 x 512)

typedef _Float16 half8 __attribute__((ext_vector_type(8)));
typedef float f32x4 __attribute__((ext_vector_type(4)));

#define WS_B1   4096
#define WS_B2   20480
#define WS_PROB 36864
#define WS_LOSS 299008
#define WS_RED  303104
#define WS_NEED 319488

#define SMEM_PRE 24064
#define SMEM_FB  155136

__device__ __forceinline__ float half_prec(const float* var_q) {
  float vq = var_q[0];
  float pq = fminf(1.0f / fmaxf(vq, 1e-5f), 1e5f);
  return 0.5f * pq;
}

// grid 16 x 512: WG0 does norms + atomic-mode zeroing; all WGs format fragments (pre mode)
__global__ void k_pre(const float* __restrict__ var_q,
                      const float* __restrict__ cb,
                      float* __restrict__ ws, int pre) {
  int t = threadIdx.x, wg = blockIdx.x;
  if (wg == 0) {
    float hp = half_prec(var_q);
    if (t == 0) ws[512] = 0.0f;
    ws[516 + t] = 0.0f;
    const float4* row = (const float4*)(cb + t * 64);
    float s = 0.0f;
    #pragma unroll
    for (int i = 0; i < 16; ++i) {
      float4 v = row[i];
      s += v.x*v.x + v.y*v.y + v.z*v.z + v.w*v.w;
    }
    ws[t] = hp * s;
  }
  if (!pre) return;
  int gid = wg * 512 + t;          // 0..8191
  if (gid < 4096) {
    // B1[tt*2+kk][l][j] = f16 cb[code=(l&15)*32+tt][dim=32*kk+8*(l>>4)+j]
    int l = gid & 63, grp = gid >> 6;
    int tt = grp >> 1, kk = grp & 1;
    int cc = l & 15, gg = l >> 4;
    const float* src = cb + (cc*32 + tt)*64 + kk*32 + gg*8;
    float4 v0 = *(const float4*)src;
    float4 v1 = *(const float4*)(src + 4);
    half8 h = { (_Float16)v0.x, (_Float16)v0.y, (_Float16)v0.z, (_Float16)v0.w,
                (_Float16)v1.x, (_Float16)v1.y, (_Float16)v1.z, (_Float16)v1.w };
    ((half8*)(ws + WS_B1))[gid] = h;
  } else {
    // B2[kt*4+nt][l][j] = f16 cb[code=((kap&15)<<5)+2*kt+(kap>>4)][dim=nt*16+(l&15)], kap=8*(l>>4)+j
    int F = gid - 4096;
    int l = F & 63, grp = F >> 6;
    int kt = grp >> 2, nt = grp & 3;
    int cc = l & 15, gg = l >> 4;
    int dim = nt*16 + cc;
    half8 h;
    #pragma unroll
    for (int j = 0; j < 8; ++j) {
      int kap = gg*8 + j;
      int code = ((kap & 15) << 5) + 2*kt + (kap >> 4);
      h[j] = (_Float16)cb[code*64 + dim];
    }
    ((half8*)(ws + WS_B2))[F] = h;
  }
}

template <int PRE>
__global__ __launch_bounds__(512) void k_main_t(
    const float* __restrict__ z, const float* __restrict__ vq,
    const float* __restrict__ cb, const float* __restrict__ gu,
    float* __restrict__ out, float* __restrict__ ws)
{
  extern __shared__ char smem[];
  constexpr int CB = PRE ? 0 : 131072;
  char*  chunkAll = smem + CB;                   // 20480 B: zc (pair) / eS (wave) / zqx (pair)
  float* pr   = (float*)(smem + CB + 20480);     // 512 f32
  float* redM = (float*)(smem + CB + 22528);     // [4 pairs][2 halves][16 rows]
  float* redS = (float*)(smem + CB + 23040);
  float* redP = (float*)(smem + CB + 23552);

  const int tid  = threadIdx.x;
  const int lane = tid & 63;
  const int wv   = tid >> 6;
  const int h    = wv & 1;        // code half: (code&31) in [16h, 16h+16)
  const int p    = wv >> 1;       // row-tile pair index (0..3)
  const int c    = lane & 15;
  const int g    = lane >> 4;

  pr[tid] = 0.0f;

  const half8* B1;
  const half8* B2;
  if constexpr (PRE) {
    B1 = (const half8*)(ws + WS_B1);
    B2 = (const half8*)(ws + WS_B2);
  } else {
    // in-LDS staging fallback (round-6 path)
    _Float16* lB1 = (_Float16*)smem;
    _Float16* lB2 = (_Float16*)(smem + 65536);
    #pragma unroll
    for (int i = 0; i < 8; ++i) {
      int F = tid + 512*i;
      int l = F & 63, grp = F >> 6;
      int t = grp >> 1, kk = grp & 1;
      int cc = l & 15, gg = l >> 4;
      const float* src = cb + (cc*32 + t)*64 + kk*32 + gg*8;
      float4 v0 = *(const float4*)src;
      float4 v1 = *(const float4*)(src + 4);
      half8 hh = { (_Float16)v0.x, (_Float16)v0.y, (_Float16)v0.z, (_Float16)v0.w,
                   (_Float16)v1.x, (_Float16)v1.y, (_Float16)v1.z, (_Float16)v1.w };
      ((half8*)lB1)[F] = hh;
    }
    #pragma unroll
    for (int i = 0; i < 8; ++i) {
      int F = tid + 512*i;
      int l = F & 63, grp = F >> 6;
      int kt = grp >> 2, nt = grp & 3;
      int cc = l & 15, gg = l >> 4;
      int dim = nt*16 + cc;
      half8 hh;
      #pragma unroll
      for (int j = 0; j < 8; ++j) {
        int kap = gg*8 + j;
        int code = ((kap & 15) << 5) + 2*kt + (kap >> 4);
        hh[j] = (_Float16)cb[code*64 + dim];
      }
      ((half8*)lB2)[F] = hh;
    }
    B1 = (const half8*)lB1;
    B2 = (const half8*)lB2;
  }

  const float hp   = half_prec(vq);
  const float s2hp = 2.0f * hp;

  const int row0 = (blockIdx.x * 4 + p) * 16;    // 16 rows per PAIR
  const int b    = row0 >> 10;
  const int wh0  = row0 & 1023;

  _Float16* zc = (_Float16*)(chunkAll + p * 5120);   // [16 rows][72 halfs], pair-shared

  // ---- z: each wave loads & stages ITS 8 rows (lane = dim), coalesced ----
  float zr[8];
  {
    const float* zp = z + ((size_t)(b*64 + lane) << 10) + wh0 + 8*h;
    float4 v0 = *(const float4*)zp;
    float4 v1 = *(const float4*)(zp + 4);
    zr[0]=v0.x; zr[1]=v0.y; zr[2]=v0.z; zr[3]=v0.w;
    zr[4]=v1.x; zr[5]=v1.y; zr[6]=v1.z; zr[7]=v1.w;
  }
  #pragma unroll
  for (int s = 0; s < 8; ++s) zc[(8*h + s)*72 + lane] = (_Float16)(zr[s] * s2hp);

  __syncthreads();   // zc (and, in FB, B1/B2) visible

  // ---- acc init: -hp*||c_k||^2 for codes c*32 + h*16 + t ----
  f32x4 acc[16];
  {
    const float4* hn = (const float4*)(ws + c*32 + h*16);
    #pragma unroll
    for (int u = 0; u < 4; ++u) {
      float4 h4 = hn[u];
      acc[4*u+0] = (f32x4){-h4.x, -h4.x, -h4.x, -h4.x};
      acc[4*u+1] = (f32x4){-h4.y, -h4.y, -h4.y, -h4.y};
      acc[4*u+2] = (f32x4){-h4.z, -h4.z, -h4.z, -h4.z};
      acc[4*u+3] = (f32x4){-h4.w, -h4.w, -h4.w, -h4.w};
    }
  }

  half8 zA0 = *(const half8*)(zc + c*72 + g*8);
  half8 zA1 = *(const half8*)(zc + c*72 + 32 + g*8);

  // ---- pass 1: 32 MFMA -> acc[t][q] = logit[row 4g+q][code c*32+h*16+t] ----
  #pragma unroll
  for (int t = 0; t < 16; ++t) {
    int tt = h*16 + t;
    acc[t] = __builtin_amdgcn_mfma_f32_16x16x32_f16(zA0, B1[(tt*2+0)*64 + lane], acc[t], 0, 0, 0);
    acc[t] = __builtin_amdgcn_mfma_f32_16x16x32_f16(zA1, B1[(tt*2+1)*64 + lane], acc[t], 0, 0, 0);
  }

  const int rix = p*32 + h*16;

  // ---- softmax max: intra-wave then cross-wave via LDS ----
  #pragma unroll
  for (int q = 0; q < 4; ++q) {
    float m = acc[0][q];
    #pragma unroll
    for (int t = 1; t < 16; ++t) m = fmaxf(m, acc[t][q]);
    #pragma unroll
    for (int o = 8; o > 0; o >>= 1) m = fmaxf(m, __shfl_xor(m, o));
    if (c == 0) redM[rix + 4*g + q] = m;
  }
  __syncthreads();
  float mq[4];
  #pragma unroll
  for (int q = 0; q < 4; ++q)
    mq[q] = fmaxf(redM[p*32 + 4*g + q], redM[p*32 + 16 + 4*g + q]);
  #pragma unroll
  for (int t = 0; t < 16; ++t)
    #pragma unroll
    for (int q = 0; q < 4; ++q) acc[t][q] -= mq[q];

  // ---- exp-sums (s1) and p*logit sums (pl) ----
  {
    float s1[4] = {0,0,0,0}, pl[4] = {0,0,0,0};
    #pragma unroll
    for (int t = 0; t < 16; ++t)
      #pragma unroll
      for (int q = 0; q < 4; ++q) {
        float e = __expf(acc[t][q]);
        s1[q] += e;
        pl[q] = fmaf(e, acc[t][q], pl[q]);
      }
    #pragma unroll
    for (int q = 0; q < 4; ++q) {
      #pragma unroll
      for (int o = 8; o > 0; o >>= 1) { s1[q] += __shfl_xor(s1[q], o); pl[q] += __shfl_xor(pl[q], o); }
      if (c == 0) { redS[rix + 4*g + q] = s1[q]; redP[rix + 4*g + q] = pl[q]; }
    }
  }
  __syncthreads();
  float kd = 0.0f, inv1[4];
  #pragma unroll
  for (int q = 0; q < 4; ++q) {
    float S = redS[p*32 + 4*g + q] + redS[p*32 + 16 + 4*g + q];
    float P = redP[p*32 + 4*g + q] + redP[p*32 + 16 + 4*g + q];
    inv1[q] = 1.0f / S;
    kd += P * inv1[q] - __logf(S);
  }

  // ---- avg-prob accumulation: code c*32+h*16+t -> pr[(h*16+t)*16 + c] ----
  #pragma unroll
  for (int t = 0; t < 16; ++t) {
    float v = 0.0f;
    #pragma unroll
    for (int q = 0; q < 4; ++q) v = fmaf(__expf(acc[t][q]), inv1[q], v);
    v += __shfl_xor(v, 16);
    v += __shfl_xor(v, 32);
    if (g == 0) atomicAdd(&pr[(h*16 + t)*16 + c], v);
  }

  // ---- gumbel: acc <- 2*(l + gv), gv = -log(-log(u+eps)+eps) ----
  #pragma unroll
  for (int q = 0; q < 4; ++q) {
    const float4* ub = (const float4*)(gu + ((size_t)(row0 + 4*g + q))*512 + c*32 + h*16);
    #pragma unroll
    for (int tt = 0; tt < 4; ++tt) {
      float4 u4 = ub[tt];
      float y0 = 1e-10f - __logf(u4.x + 1e-10f);
      float y1 = 1e-10f - __logf(u4.y + 1e-10f);
      float y2 = 1e-10f - __logf(u4.z + 1e-10f);
      float y3 = 1e-10f - __logf(u4.w + 1e-10f);
      acc[4*tt+0][q] = 2.0f * (acc[4*tt+0][q] - __logf(y0));
      acc[4*tt+1][q] = 2.0f * (acc[4*tt+1][q] - __logf(y1));
      acc[4*tt+2][q] = 2.0f * (acc[4*tt+2][q] - __logf(y2));
      acc[4*tt+3][q] = 2.0f * (acc[4*tt+3][q] - __logf(y3));
    }
  }

  // ---- encoding softmax: max then sum, pair-combined ----
  #pragma unroll
  for (int q = 0; q < 4; ++q) {
    float m = acc[0][q];
    #pragma unroll
    for (int t = 1; t < 16; ++t) m = fmaxf(m, acc[t][q]);
    #pragma unroll
    for (int o = 8; o > 0; o >>= 1) m = fmaxf(m, __shfl_xor(m, o));
    if (c == 0) redM[rix + 4*g + q] = m;
  }
  __syncthreads();
  #pragma unroll
  for (int q = 0; q < 4; ++q) {
    float m2 = fmaxf(redM[p*32 + 4*g + q], redM[p*32 + 16 + 4*g + q]);
    float s = 0.0f;
    #pragma unroll
    for (int t = 0; t < 16; ++t) { float e = __expf(acc[t][q] - m2); acc[t][q] = e; s += e; }
    #pragma unroll
    for (int o = 8; o > 0; o >>= 1) s += __shfl_xor(s, o);
    if (c == 0) redS[rix + 4*g + q] = s;
  }
  __syncthreads();
  #pragma unroll
  for (int q = 0; q < 4; ++q) {
    float inv = 1.0f / (redS[p*32 + 4*g + q] + redS[p*32 + 16 + 4*g + q]);
    #pragma unroll
    for (int t = 0; t < 16; ++t) acc[t][q] *= inv;
  }

  // ---- pass 2: partial zq over this wave's 256 codes ----
  f32x4 zacc[4];
  #pragma unroll
  for (int nt = 0; nt < 4; ++nt) zacc[nt] = (f32x4){0.f, 0.f, 0.f, 0.f};

  _Float16* myES = (_Float16*)(chunkAll + wv * 2560);
  #pragma unroll
  for (int k = 0; k < 8; ++k) {
    _Float16* eS = myES + (k & 1) * 640;     // [16 rows][40 halfs], wave-private
    #pragma unroll
    for (int tb = 0; tb < 2; ++tb)
      #pragma unroll
      for (int q = 0; q < 4; ++q)
        eS[(4*g + q)*40 + 16*tb + c] = (_Float16)acc[2*k + tb][q];
    half8 ea = *(const half8*)(eS + c*40 + g*8);
    int kt = h*8 + k;
    #pragma unroll
    for (int nt = 0; nt < 4; ++nt)
      zacc[nt] = __builtin_amdgcn_mfma_f32_16x16x32_f16(ea, B2[(kt*4 + nt)*64 + lane], zacc[nt], 0, 0, 0);
  }

  // ---- pair-sum zq through LDS, transpose-store + continuous KLD ----
  __syncthreads();
  float* zqx = (float*)chunkAll + p * 1056;          // [16 rows][66 f32], pair-shared
  if (h) {
    #pragma unroll
    for (int nt = 0; nt < 4; ++nt)
      #pragma unroll
      for (int q = 0; q < 4; ++q)
        zqx[(4*g + q)*66 + nt*16 + c] = zacc[nt][q];
  }
  __syncthreads();
  if (!h) {
    #pragma unroll
    for (int nt = 0; nt < 4; ++nt)
      #pragma unroll
      for (int q = 0; q < 4; ++q) {
        int ix = (4*g + q)*66 + nt*16 + c;
        zqx[ix] += zacc[nt][q];
      }
  }
  __syncthreads();

  float kc = 0.0f;
  {
    float* orow = out + ((size_t)(b*64 + lane) << 10) + wh0 + 8*h;
    float4 o0, o1;
    o0.x = zqx[(8*h + 0)*66 + lane]; o0.y = zqx[(8*h + 1)*66 + lane];
    o0.z = zqx[(8*h + 2)*66 + lane]; o0.w = zqx[(8*h + 3)*66 + lane];
    o1.x = zqx[(8*h + 4)*66 + lane]; o1.y = zqx[(8*h + 5)*66 + lane];
    o1.z = zqx[(8*h + 6)*66 + lane]; o1.w = zqx[(8*h + 7)*66 + lane];
    float d;
    d = zr[0]-o0.x; kc = fmaf(d,d,kc);  d = zr[1]-o0.y; kc = fmaf(d,d,kc);
    d = zr[2]-o0.z; kc = fmaf(d,d,kc);  d = zr[3]-o0.w; kc = fmaf(d,d,kc);
    d = zr[4]-o1.x; kc = fmaf(d,d,kc);  d = zr[5]-o1.y; kc = fmaf(d,d,kc);
    d = zr[6]-o1.z; kc = fmaf(d,d,kc);  d = zr[7]-o1.w; kc = fmaf(d,d,kc);
    *(float4*)orow       = o0;
    *(float4*)(orow + 4) = o1;
  }
  kc *= hp;

  // ---- loss partial ----
  float lv = (h ? 0.0f : kd * 0.0625f) + kc;
  #pragma unroll
  for (int o = 32; o > 0; o >>= 1) lv += __shfl_xor(lv, o);
  if (lane == 0) {
    if constexpr (PRE) ws[WS_LOSS + blockIdx.x*8 + wv] = lv;
    else               atomicAdd(&ws[512], lv);
  }

  __syncthreads();
  if constexpr (PRE) {
    ws[WS_PROB + (size_t)blockIdx.x*512 + tid] = pr[tid];
  } else {
    atomicAdd(ws + 516 + tid, pr[tid]);
  }
}

__global__ void k_red(float* __restrict__ ws) {
  int gix = blockIdx.x, t = threadIdx.x;   // 32 x 512
  float s = 0.0f;
  #pragma unroll 4
  for (int i = 0; i < 16; ++i) s += ws[WS_PROB + (size_t)(gix*16 + i)*512 + t];
  ws[WS_RED + gix*512 + t] = s;
}

__global__ void k_fin(const float* __restrict__ ws, float* __restrict__ out, int pre) {
  __shared__ float redH[16], redL[16];
  int t = threadIdx.x;  // 1024
  float h = 0.0f, l = 0.0f;
  if (pre) {
    if (t < 512) {
      float s = 0.0f;
      #pragma unroll
      for (int g = 0; g < 32; ++g) s += ws[WS_RED + g*512 + t];
      float a = fmaxf(s * (1.0f/32768.0f), 1e-10f);
      h = -a * __logf(a + 1e-10f);
    } else {
      int x = t - 512;
      #pragma unroll
      for (int i = 0; i < 8; ++i) l += ws[WS_LOSS + x + 512*i];
    }
  } else {
    if (t < 512) {
      float a = fmaxf(ws[516 + t] * (1.0f/32768.0f), 1e-10f);
      h = -a * __logf(a + 1e-10f);
    } else if (t == 512) {
      l = ws[512];
    }
  }
  #pragma unroll
  for (int o = 32; o > 0; o >>= 1) { h += __shfl_xor(h, o); l += __shfl_xor(l, o); }
  if ((t & 63) == 0) { redH[t >> 6] = h; redL[t >> 6] = l; }
  __syncthreads();
  if (t == 0) {
    float H = 0.0f, L = 0.0f;
    #pragma unroll
    for (int i = 0; i < 16; ++i) { H += redH[i]; L += redL[i]; }
    out[2097152] = L * (1.0f/32.0f);
    out[2097153] = __expf(H);
  }
}

extern "C" void kernel_launch(void* const* d_in, const int* in_sizes, int n_in,
                              void* d_out, int out_size, void* d_ws, size_t ws_size,
                              hipStream_t stream) {
  const float* z  = (const float*)d_in[0];
  const float* vq = (const float*)d_in[1];
  const float* cb = (const float*)d_in[2];
  const float* gu = (const float*)d_in[3];
  float* out = (float*)d_out;
  float* ws  = (float*)d_ws;
  int pre = (ws_size >= (size_t)WS_NEED * 4) ? 1 : 0;

  hipLaunchKernelGGL(k_pre, dim3(16), dim3(512), 0, stream, vq, cb, ws, pre);
  if (pre) {
    hipLaunchKernelGGL(k_main_t<1>, dim3(512), dim3(512), SMEM_PRE, stream, z, vq, cb, gu, out, ws);
    hipLaunchKernelGGL(k_red, dim3(32), dim3(512), 0, stream, ws);
  } else {
    hipFuncSetAttribute((const void*)&k_main_t<0>, hipFuncAttributeMaxDynamicSharedMemorySize, SMEM_FB);
    hipLaunchKernelGGL(k_main_t<0>, dim3(512), dim3(512), SMEM_FB, stream, z, vq, cb, gu, out, ws);
  }
  hipLaunchKernelGGL(k_fin, dim3(1), dim3(1024), 0, stream, ws, out, pre);
}